// Round 17
// baseline (14.892 us; speedup 1.0000x reference)
//
#include <hip/hip_runtime.h>
#include <hip/hip_bf16.h>

// Shapes: x,gn (8,128,64) f32; fb (1,128,32768) f32; resonance (64,128) f32.
// out (8,1,32768) f32.
// r[b,c,f] = sum_rr softmax(x+gn)[b,c,rr] * res[rr,f]
// out[b,s] = (1/128) * sum_c lerp(r[b,c,:], s) * fb[c,s]
//
// Fused v7 = R16 (13.6us) with p2 band-split across waves.
// R16 lesson: p2 is mixed issue+latency bound; dedup halved instrs but also
// halved active waves. v7 halves issue counts AGAIN while keeping all 8
// waves: wave = (band-group bg 0..3, sample-half sh 0..1); thread = 4
// consecutive samples x 32 bands x both batches. Per CU: DS 256 b128 (2-way
// broadcast, free), VMEM 256 float4 (same bytes, half instrs), 8 waves
// hiding latency. Band partials (4 per output) reduced via 16KB LDS + 2nd
// barrier. fb still read exactly once per block; bp-major order keeps the
// 4 blocks sharing a seg's fb slice on one XCD (bi%8 == seg%8).

#define BATCH 8
#define BANDS 128
#define RES 64
#define NF 128
#define NS 32768
#define SEG 512
#define NSEG (NS / SEG)    // 64
#define NBP 4              // batch pairs
#define NTHR 512

__global__ __launch_bounds__(NTHR) void fused(const float* __restrict__ x,
                                              const float* __restrict__ gn,
                                              const float* __restrict__ fb,
                                              const float* __restrict__ res,
                                              float* __restrict__ out) {
    const int bi   = blockIdx.x;      // 0..255, bp-major
    const int bp   = bi >> 6;         // 0..3
    const int seg  = bi & 63;         // 0..63
    const int tid  = threadIdx.x;     // 0..511
    const int lane = tid & 63;
    const int wv   = tid >> 6;        // 0..7

    __shared__ float resc[4][RES];      // staged res columns [frame][rr]
    __shared__ float r4[4][256];        // r per frame, row = bl*128+c
    __shared__ float part[4][2][SEG];   // band-group partials [bg][bl][sample]

    const int fbase = 2 * seg - 1;    // lo in {2seg-1..2seg+1}; il=lo-fbase in 0..2

    if (tid < 4 * RES) {
        const int rr = tid >> 2, j = tid & 3;
        const int f = min(max(fbase + j, 0), NF - 1);
        resc[j][rr] = res[rr * NF + f];
    }
    __syncthreads();

    // ---- hoist this lane's resc slice (16 elems x 4 frames) to registers ----
    const int e0 = (tid & 3) * 16;
    float4 cr[4][4];
    #pragma unroll
    for (int f = 0; f < 4; ++f)
        #pragma unroll
        for (int j = 0; j < 4; ++j)
            cr[f][j] = *(const float4*)&resc[f][e0 + 4 * j];

    // ---- Phase 1: 256 rows (2 batches x 128 bands), 2 passes, 4 lanes/row ----
    const int q = tid >> 2;
    #pragma unroll
    for (int p = 0; p < 2; ++p) {
        const int row = p * 128 + q;
        const int bl  = row >> 7;
        const int c   = row & 127;
        const int bc  = (2 * bp + bl) * BANDS + c;

        const float4* __restrict__ xp = (const float4*)(x  + bc * RES + e0);
        const float4* __restrict__ gp = (const float4*)(gn + bc * RES + e0);

        float s = 0.f, d0 = 0.f, d1 = 0.f, d2 = 0.f, d3 = 0.f;
        #pragma unroll
        for (int j = 0; j < 4; ++j) {
            const float4 a = xp[j];
            const float4 b = gp[j];
            const float ex = __expf(a.x + b.x);
            const float ey = __expf(a.y + b.y);
            const float ez = __expf(a.z + b.z);
            const float ew = __expf(a.w + b.w);
            s += (ex + ey) + (ez + ew);
            d0 = fmaf(ex, cr[0][j].x, fmaf(ey, cr[0][j].y, fmaf(ez, cr[0][j].z, fmaf(ew, cr[0][j].w, d0))));
            d1 = fmaf(ex, cr[1][j].x, fmaf(ey, cr[1][j].y, fmaf(ez, cr[1][j].z, fmaf(ew, cr[1][j].w, d1))));
            d2 = fmaf(ex, cr[2][j].x, fmaf(ey, cr[2][j].y, fmaf(ez, cr[2][j].z, fmaf(ew, cr[2][j].w, d2))));
            d3 = fmaf(ex, cr[3][j].x, fmaf(ey, cr[3][j].y, fmaf(ez, cr[3][j].z, fmaf(ew, cr[3][j].w, d3))));
        }
        s  += __shfl_xor(s, 1);  s  += __shfl_xor(s, 2);
        d0 += __shfl_xor(d0, 1); d0 += __shfl_xor(d0, 2);
        d1 += __shfl_xor(d1, 1); d1 += __shfl_xor(d1, 2);
        d2 += __shfl_xor(d2, 1); d2 += __shfl_xor(d2, 2);
        d3 += __shfl_xor(d3, 1); d3 += __shfl_xor(d3, 2);

        if ((tid & 3) == 0) {
            const float inv = 1.0f / s;
            r4[0][row] = d0 * inv;
            r4[1][row] = d1 * inv;
            r4[2][row] = d2 * inv;
            r4[3][row] = d3 * inv;
        }
    }
    __syncthreads();

    // ---- Phase 2: wave = (bg = wv>>1, sh = wv&1); thread = 4 samples x
    //      32 bands (bg*32..+31) x both batches ----
    const int bg  = wv >> 1;          // band group 0..3
    const int sh  = wv & 1;           // sample half 0..1
    const int sl0 = sh * 256 + (lane << 2);   // sample offset in seg
    const int s0  = seg * SEG + sl0;

    float w0, w1, w2, w3;
    int il;
    {
        float pv[4];
        #pragma unroll
        for (int i = 0; i < 4; ++i) {
            float p = ((float)(s0 + i) + 0.5f) * (1.0f / 256.0f) - 0.5f;
            pv[i] = fminf(fmaxf(p, 0.0f), (float)(NF - 1));
        }
        const int lo = (int)floorf(pv[0]);   // uniform over the 4-sample group
        il = lo - fbase;                     // 0..2, per-lane (<=2 addrs/wave)
        w0 = pv[0] - (float)lo; w1 = pv[1] - (float)lo;
        w2 = pv[2] - (float)lo; w3 = pv[3] - (float)lo;
    }

    const float* __restrict__ rlp = &r4[il][0];
    const float* __restrict__ rhp = &r4[il + 1][0];
    const int c0 = bg * 32;

    float4 acc0 = {0.f, 0.f, 0.f, 0.f};
    float4 acc1 = {0.f, 0.f, 0.f, 0.f};

    #pragma unroll
    for (int g = 0; g < 8; ++g) {
        const int cb = c0 + g * 4;
        const float4 f0 = *(const float4*)&fb[(cb + 0) * NS + s0];
        const float4 f1 = *(const float4*)&fb[(cb + 1) * NS + s0];
        const float4 f2 = *(const float4*)&fb[(cb + 2) * NS + s0];
        const float4 f3 = *(const float4*)&fb[(cb + 3) * NS + s0];

        {   // batch 0
            const float4 rl4 = *(const float4*)&rlp[cb];
            const float4 rh4 = *(const float4*)&rhp[cb];
            const float dx = rh4.x - rl4.x, dy = rh4.y - rl4.y;
            const float dz = rh4.z - rl4.z, dw = rh4.w - rl4.w;
            acc0.x = fmaf(f0.x, fmaf(w0, dx, rl4.x), acc0.x);
            acc0.y = fmaf(f0.y, fmaf(w1, dx, rl4.x), acc0.y);
            acc0.z = fmaf(f0.z, fmaf(w2, dx, rl4.x), acc0.z);
            acc0.w = fmaf(f0.w, fmaf(w3, dx, rl4.x), acc0.w);
            acc0.x = fmaf(f1.x, fmaf(w0, dy, rl4.y), acc0.x);
            acc0.y = fmaf(f1.y, fmaf(w1, dy, rl4.y), acc0.y);
            acc0.z = fmaf(f1.z, fmaf(w2, dy, rl4.y), acc0.z);
            acc0.w = fmaf(f1.w, fmaf(w3, dy, rl4.y), acc0.w);
            acc0.x = fmaf(f2.x, fmaf(w0, dz, rl4.z), acc0.x);
            acc0.y = fmaf(f2.y, fmaf(w1, dz, rl4.z), acc0.y);
            acc0.z = fmaf(f2.z, fmaf(w2, dz, rl4.z), acc0.z);
            acc0.w = fmaf(f2.w, fmaf(w3, dz, rl4.z), acc0.w);
            acc0.x = fmaf(f3.x, fmaf(w0, dw, rl4.w), acc0.x);
            acc0.y = fmaf(f3.y, fmaf(w1, dw, rl4.w), acc0.y);
            acc0.z = fmaf(f3.z, fmaf(w2, dw, rl4.w), acc0.z);
            acc0.w = fmaf(f3.w, fmaf(w3, dw, rl4.w), acc0.w);
        }
        {   // batch 1
            const float4 rl4 = *(const float4*)&rlp[128 + cb];
            const float4 rh4 = *(const float4*)&rhp[128 + cb];
            const float dx = rh4.x - rl4.x, dy = rh4.y - rl4.y;
            const float dz = rh4.z - rl4.z, dw = rh4.w - rl4.w;
            acc1.x = fmaf(f0.x, fmaf(w0, dx, rl4.x), acc1.x);
            acc1.y = fmaf(f0.y, fmaf(w1, dx, rl4.x), acc1.y);
            acc1.z = fmaf(f0.z, fmaf(w2, dx, rl4.x), acc1.z);
            acc1.w = fmaf(f0.w, fmaf(w3, dx, rl4.x), acc1.w);
            acc1.x = fmaf(f1.x, fmaf(w0, dy, rl4.y), acc1.x);
            acc1.y = fmaf(f1.y, fmaf(w1, dy, rl4.y), acc1.y);
            acc1.z = fmaf(f1.z, fmaf(w2, dy, rl4.y), acc1.z);
            acc1.w = fmaf(f1.w, fmaf(w3, dy, rl4.y), acc1.w);
            acc1.x = fmaf(f2.x, fmaf(w0, dz, rl4.z), acc1.x);
            acc1.y = fmaf(f2.y, fmaf(w1, dz, rl4.z), acc1.y);
            acc1.z = fmaf(f2.z, fmaf(w2, dz, rl4.z), acc1.z);
            acc1.w = fmaf(f2.w, fmaf(w3, dz, rl4.z), acc1.w);
            acc1.x = fmaf(f3.x, fmaf(w0, dw, rl4.w), acc1.x);
            acc1.y = fmaf(f3.y, fmaf(w1, dw, rl4.w), acc1.y);
            acc1.z = fmaf(f3.z, fmaf(w2, dw, rl4.w), acc1.z);
            acc1.w = fmaf(f3.w, fmaf(w3, dw, rl4.w), acc1.w);
        }
    }

    *(float4*)&part[bg][0][sl0] = acc0;
    *(float4*)&part[bg][1][sl0] = acc1;
    __syncthreads();

    // ---- Reduce over band groups: thread = (bl = tid>>8, sample pair) ----
    const int bl2 = tid >> 8;         // 0..1
    const int sp  = tid & 255;        // 0..255
    const int ss  = sp * 2;           // even sample offset in seg
    const float2 v0 = *(const float2*)&part[0][bl2][ss];
    const float2 v1 = *(const float2*)&part[1][bl2][ss];
    const float2 v2 = *(const float2*)&part[2][bl2][ss];
    const float2 v3 = *(const float2*)&part[3][bl2][ss];
    float2 o;
    o.x = ((v0.x + v1.x) + (v2.x + v3.x)) * (1.0f / (float)BANDS);
    o.y = ((v0.y + v1.y) + (v2.y + v3.y)) * (1.0f / (float)BANDS);
    *(float2*)&out[(2 * bp + bl2) * NS + seg * SEG + ss] = o;
}

extern "C" void kernel_launch(void* const* d_in, const int* in_sizes, int n_in,
                              void* d_out, int out_size, void* d_ws, size_t ws_size,
                              hipStream_t stream) {
    const float* x   = (const float*)d_in[0];
    const float* gn  = (const float*)d_in[1];
    const float* fb  = (const float*)d_in[2];
    const float* res = (const float*)d_in[3];
    float* out = (float*)d_out;

    fused<<<NBP * NSEG, NTHR, 0, stream>>>(x, gn, fb, res, out);
}